// Round 7
// baseline (476.038 us; speedup 1.0000x reference)
//
#include <hip/hip_runtime.h>
#include <hip/hip_bf16.h>

typedef unsigned short u16;
typedef unsigned int   u32;
typedef __attribute__((ext_vector_type(8))) short short8;
typedef __attribute__((ext_vector_type(4))) float f32x4;

#define NN 320
#define NP (NN*NN)
#define DD 128
#define NH 4
#define DHH 32
#define QSCALE 0.17677669529663687f
#define LOG2E  1.4426950408889634f

#define MFMA16(A,B,C) __builtin_amdgcn_mfma_f32_16x16x32_bf16(A,B,C,0,0,0)

__device__ __forceinline__ float b2f(u16 u){
    union { u32 i; float f; } v; v.i = ((u32)u) << 16; return v.f;
}
__device__ __forceinline__ u16 f2b(float f){
    union { float f; u32 i; } v; v.f = f;
    u32 x = v.i;
    u32 r = x + 0x7fffu + ((x >> 16) & 1u);
    return (u16)(r >> 16);
}
__device__ __forceinline__ u32 cvtpk(float lo, float hi){
    u32 r; asm("v_cvt_pk_bf16_f32 %0, %1, %2" : "=v"(r) : "v"(lo), "v"(hi)); return r;
}
__device__ __forceinline__ float fexp2(float x){
    float r; asm("v_exp_f32 %0, %1" : "=v"(r) : "v"(x)); return r;
}
__device__ __forceinline__ float frcp(float x){
    float r; asm("v_rcp_f32 %0, %1" : "=v"(r) : "v"(x)); return r;
}

// ---------------- Weight pre-pack: f32 [e][k] -> bf16 fragment-ordered ----------------
// Wp[m][e*16 + slot][8] ; flat copy since (e*16+slot)*8 == e*128 + slot*8.
__global__ __launch_bounds__(256) void k_pack(
    const float* w0, const float* w1, const float* w2, const float* w3, const float* w4,
    const float* w5, const float* w6, const float* w7, const float* w8, const float* w9,
    u16* __restrict__ Wp)
{
    const int m = blockIdx.x >> 3;                       // 10 mats, 8 blocks each
    const int rem = ((blockIdx.x & 7) << 8) + threadIdx.x;  // 0..2047
    const float* src;
    switch(m){
        case 0: src=w0; break; case 1: src=w1; break; case 2: src=w2; break;
        case 3: src=w3; break; case 4: src=w4; break; case 5: src=w5; break;
        case 6: src=w6; break; case 7: src=w7; break; case 8: src=w8; break;
        default: src=w9; break;
    }
    const float4 a = *(const float4*)(src + (size_t)rem*8);
    const float4 b = *(const float4*)(src + (size_t)rem*8 + 4);
    union { uint4 q; u16 us[8]; } ww;
    ww.us[0]=f2b(a.x); ww.us[1]=f2b(a.y); ww.us[2]=f2b(a.z); ww.us[3]=f2b(a.w);
    ww.us[4]=f2b(b.x); ww.us[5]=f2b(b.y); ww.us[6]=f2b(b.z); ww.us[7]=f2b(b.w);
    *(uint4*)(Wp + ((size_t)m*2048 + rem)*8) = ww.q;
}

// ---------------- LayerNorm + edge-bias kernel ----------------
__global__ __launch_bounds__(256) void k_ln_bias(
    const float* __restrict__ xin, const float* __restrict__ ng, const float* __restrict__ nb,
    const float* __restrict__ wb, u16* __restrict__ xn, float* __restrict__ bias)
{
    const int w = threadIdx.x >> 6, lane = threadIdx.x & 63;
    const int p = blockIdx.x * 4 + w;
    const int d0 = lane * 2;
    const float2 xp = *(const float2*)(xin + (size_t)p*DD + d0);
    const float x0 = xp.x, x1 = xp.y;
    float s = x0 + x1;
    #pragma unroll
    for (int m = 1; m < 64; m <<= 1) s += __shfl_xor(s, m);
    const float mu = s * (1.f/128.f);
    const float dx0 = x0 - mu, dx1 = x1 - mu;
    float vv = dx0*dx0 + dx1*dx1;
    #pragma unroll
    for (int m = 1; m < 64; m <<= 1) vv += __shfl_xor(vv, m);
    const float rstd = rsqrtf(vv * (1.f/128.f) + 1e-5f);
    const float2 gp = *(const float2*)(ng + d0);
    const float2 bp = *(const float2*)(nb + d0);
    const float y0 = dx0*rstd*gp.x + bp.x;
    const float y1 = dx1*rstd*gp.y + bp.y;
    const u32 ow = (u32)f2b(y0) | ((u32)f2b(y1) << 16);
    *(u32*)(xn + (size_t)p*DD + d0) = ow;
    #pragma unroll
    for (int h = 0; h < NH; ++h){
        const float2 wp = *(const float2*)(wb + h*DD + d0);
        float bb = x0*wp.x + x1*wp.y;
        #pragma unroll
        for (int m = 1; m < 64; m <<= 1) bb += __shfl_xor(bb, m);
        if (lane == 0) bias[(size_t)h*NP + p] = bb * LOG2E;
    }
}

// ---------------- Fused QKVG GEMM: A staged once, W-frags from packed global ----------------
// p=0: Q (*QSCALE*LOG2E)  p=1: K  p=2: V  p=3: G (sigmoid(+bg))
__global__ __launch_bounds__(256) void k_qkvg(
    const u16* __restrict__ Amat, const u16* __restrict__ Wp, const float* __restrict__ bg,
    u16* __restrict__ Pq, u16* __restrict__ Pk, u16* __restrict__ Pv, u16* __restrict__ Pg)
{
    __shared__ u16 As[128*128];   // [row][k], 16B-slot swizzle: slot ^= row&7
    const int tid = threadIdx.x;
    const int pbase = blockIdx.x * 128;

    #pragma unroll
    for (int c = 0; c < 8; ++c){
        const int flat = tid + c*256;
        const int row = flat >> 4, s = flat & 15;
        const uint4 a4 = *(const uint4*)(Amat + (size_t)(pbase+row)*DD + s*8);
        *(uint4*)&As[row*128 + ((s ^ (row & 7)) << 3)] = a4;
    }
    __syncthreads();

    const int w = tid >> 6, l = tid & 63;
    const int li = l & 15, g = l >> 4;
    const int wr = w >> 1, wc = w & 1;

    #pragma unroll
    for (int p = 0; p < 4; ++p){
        f32x4 acc[4][4] = {};
        #pragma unroll
        for (int ks = 0; ks < 4; ++ks){
            const int slot = ks*4 + g;
            short8 af[4];
            #pragma unroll
            for (int mt = 0; mt < 4; ++mt){
                const int row = wr*64 + mt*16 + li;
                af[mt] = *(const short8*)&As[row*128 + ((slot ^ (row & 7)) << 3)];
            }
            #pragma unroll
            for (int nt = 0; nt < 4; ++nt){
                const int e = wc*64 + nt*16 + li;
                const short8 wf = *(const short8*)(Wp + ((size_t)p*2048 + e*16 + slot)*8);
                #pragma unroll
                for (int mt = 0; mt < 4; ++mt)
                    acc[mt][nt] = MFMA16(af[mt], wf, acc[mt][nt]);
            }
        }

        u16* Op = (p == 0) ? Pq : (p == 1) ? Pk : (p == 2) ? Pv : Pg;
        #pragma unroll
        for (int mt = 0; mt < 4; ++mt){
            #pragma unroll
            for (int nt = 0; nt < 4; ++nt){
                const int e = wc*64 + nt*16 + li;
                #pragma unroll
                for (int q = 0; q < 4; ++q){
                    const size_t pos = (size_t)pbase + wr*64 + mt*16 + g*4 + q;
                    float v = acc[mt][nt][q];
                    if (p == 0) v *= (QSCALE * LOG2E);
                    else if (p == 3) v = frcp(1.f + fexp2(-LOG2E*(v + bg[e])));
                    Op[pos*DD + e] = f2b(v);
                }
            }
        }
    }
}

// ---------------- Output projection: A = Aatt*Pg (gated in staging), +bo +res -> f32 ----------------
__global__ __launch_bounds__(256) void k_oproj(
    const u16* __restrict__ Aatt, const u16* __restrict__ Pg, const u16* __restrict__ Wp,
    float* __restrict__ Outp, const float* __restrict__ bov, const float* __restrict__ xres)
{
    __shared__ u16 As[128*128];
    const int tid = threadIdx.x;
    const int pbase = blockIdx.x * 128;

    #pragma unroll
    for (int c = 0; c < 8; ++c){
        const int flat = tid + c*256;
        const int row = flat >> 4, s = flat & 15;
        const size_t off = (size_t)(pbase+row)*DD + s*8;
        union { uint4 q; u16 us[8]; } ua, ug;
        ua.q = *(const uint4*)(Aatt + off);
        ug.q = *(const uint4*)(Pg + off);
        uint4 o;
        o.x = cvtpk(b2f(ua.us[0])*b2f(ug.us[0]), b2f(ua.us[1])*b2f(ug.us[1]));
        o.y = cvtpk(b2f(ua.us[2])*b2f(ug.us[2]), b2f(ua.us[3])*b2f(ug.us[3]));
        o.z = cvtpk(b2f(ua.us[4])*b2f(ug.us[4]), b2f(ua.us[5])*b2f(ug.us[5]));
        o.w = cvtpk(b2f(ua.us[6])*b2f(ug.us[6]), b2f(ua.us[7])*b2f(ug.us[7]));
        *(uint4*)&As[row*128 + ((s ^ (row & 7)) << 3)] = o;
    }
    __syncthreads();

    const int w = tid >> 6, l = tid & 63;
    const int li = l & 15, g = l >> 4;
    const int wr = w >> 1, wc = w & 1;
    f32x4 acc[4][4] = {};

    #pragma unroll
    for (int ks = 0; ks < 4; ++ks){
        const int slot = ks*4 + g;
        short8 af[4];
        #pragma unroll
        for (int mt = 0; mt < 4; ++mt){
            const int row = wr*64 + mt*16 + li;
            af[mt] = *(const short8*)&As[row*128 + ((slot ^ (row & 7)) << 3)];
        }
        #pragma unroll
        for (int nt = 0; nt < 4; ++nt){
            const int e = wc*64 + nt*16 + li;
            const short8 wf = *(const short8*)(Wp + ((size_t)4*2048 + e*16 + slot)*8);
            #pragma unroll
            for (int mt = 0; mt < 4; ++mt)
                acc[mt][nt] = MFMA16(af[mt], wf, acc[mt][nt]);
        }
    }

    #pragma unroll
    for (int mt = 0; mt < 4; ++mt){
        #pragma unroll
        for (int nt = 0; nt < 4; ++nt){
            const int e = wc*64 + nt*16 + li;
            #pragma unroll
            for (int q = 0; q < 4; ++q){
                const size_t pos = (size_t)pbase + wr*64 + mt*16 + g*4 + q;
                Outp[pos*DD + e] = acc[mt][nt][q] + bov[e] + xres[pos*DD + e];
            }
        }
    }
}

// ---------------- MFMA attention: one block per (h, r), 4 waves x 5 Q-tiles ----------------
// 2-chunk online softmax (halves score VGPRs); bias as C-operand;
// V staged j-permuted (zero-shuffle PV); denominators via ones-MFMA; gate applied in oproj.
// NOTE: no min-waves launch_bounds hint — (256,3)/(256,4) hints correlate with miscompiles (r4/r6 NaN).
template<int ROWPASS>
__global__ __launch_bounds__(256) void k_attn_mfma(
    const u16* __restrict__ Pq, const u16* __restrict__ Pk, const u16* __restrict__ Pv,
    const float* __restrict__ bias, u16* __restrict__ Aout)
{
    __shared__ u16 ksm[320*32];  // [j][e], 16B-slot swizzle: slot ^= (j>>1)&3
    __shared__ u16 vt[32*320];   // [e][j'], j' = PV-permuted j, slot swizzle: slot ^= e&7
    const int h = blockIdx.x, r = blockIdx.y;
    const int tid = threadIdx.x;

    #pragma unroll
    for (int c = 0; c < 5; ++c){
        const int flat = tid + c*256;      // 0..1279
        const int j = flat >> 2, s = flat & 3;
        const size_t pos = ROWPASS ? ((size_t)r*NN + j) : ((size_t)j*NN + r);
        const uint4 k4 = *(const uint4*)(Pk + pos*DD + h*DHH + s*8);
        *(uint4*)&ksm[j*32 + ((s ^ ((j >> 1) & 3)) << 3)] = k4;
        const uint4 v4 = *(const uint4*)(Pv + pos*DD + h*DHH + s*8);
        union { uint4 q; u16 us[8]; } vu; vu.q = v4;
        const int jp = (j & ~31) + ((j >> 2) & 3)*8 + ((j >> 4) & 1)*4 + (j & 3);
        #pragma unroll
        for (int u = 0; u < 8; ++u){
            const int e = s*8 + u;
            vt[e*320 + (((jp >> 3) ^ (e & 7)) << 3) + (jp & 7)] = vu.us[u];
        }
    }
    __syncthreads();

    const int w = tid >> 6, l = tid & 63;
    const int li = l & 15, g = l >> 4;
    const short8 ones = {0x3F80,0x3F80,0x3F80,0x3F80,0x3F80,0x3F80,0x3F80,0x3F80};

    for (int t = 0; t < 5; ++t){
        const int i0 = (w + t*4) * 16;
        const int iq = i0 + li;
        const size_t qpos = ROWPASS ? ((size_t)r*NN + iq) : ((size_t)iq*NN + r);
        const short8 qf = *(const short8*)(Pq + qpos*DD + h*DHH + g*8);

        float mrun = -3.0e38f;
        f32x4 o0 = {0.f,0.f,0.f,0.f}, o1 = {0.f,0.f,0.f,0.f}, osum = {0.f,0.f,0.f,0.f};

        #pragma unroll
        for (int ch = 0; ch < 2; ++ch){
            // bias -> C operands for this chunk (10 tiles of 16 j)
            f32x4 st[10];
            const float* bp = bias + (size_t)h*NP + (size_t)iq*NN + ch*160 + g*4;
            #pragma unroll
            for (int jt = 0; jt < 10; ++jt)
                st[jt] = *(const f32x4*)(bp + jt*16);

            #pragma unroll
            for (int jt = 0; jt < 10; ++jt){
                const int jr = ch*160 + jt*16 + li;
                const short8 kf = *(const short8*)&ksm[jr*32 + ((g ^ ((jr >> 1) & 3)) << 3)];
                st[jt] = MFMA16(kf, qf, st[jt]);
            }

            // chunk max -> online rescale
            float mx = -3.0e38f;
            #pragma unroll
            for (int jt = 0; jt < 10; ++jt)
                mx = fmaxf(mx, fmaxf(fmaxf(st[jt][0], st[jt][1]), fmaxf(st[jt][2], st[jt][3])));
            mx = fmaxf(mx, __shfl_xor(mx, 16));
            mx = fmaxf(mx, __shfl_xor(mx, 32));
            const float mnew = fmaxf(mrun, mx);
            const float sc = fexp2(mrun - mnew);
            #pragma unroll
            for (int q = 0; q < 4; ++q){
                o0[q] *= sc; o1[q] *= sc; osum[q] *= sc;
            }
            mrun = mnew;

            #pragma unroll
            for (int jt = 0; jt < 10; ++jt){
                #pragma unroll
                for (int q = 0; q < 4; ++q)
                    st[jt][q] = fexp2(st[jt][q] - mrun);
            }

            // PV + denominator (zero shuffles; vt pre-permuted)
            #pragma unroll
            for (int kt = 0; kt < 5; ++kt){
                union { u32 u[4]; short8 s8; } pu;
                pu.u[0] = cvtpk(st[2*kt][0],   st[2*kt][1]);
                pu.u[1] = cvtpk(st[2*kt][2],   st[2*kt][3]);
                pu.u[2] = cvtpk(st[2*kt+1][0], st[2*kt+1][1]);
                pu.u[3] = cvtpk(st[2*kt+1][2], st[2*kt+1][3]);
                const int ktg = ch*5 + kt;
                const int slot = ((ktg*4 + g) ^ (li & 7)) << 3;
                const short8 v0 = *(const short8*)&vt[li*320 + slot];
                const short8 v1 = *(const short8*)&vt[(16+li)*320 + slot];
                o0   = MFMA16(pu.s8, v0,   o0);
                o1   = MFMA16(pu.s8, v1,   o1);
                osum = MFMA16(pu.s8, ones, osum);
            }
        }

        // epilogue: rows i = i0+4g+q (osum matches; no shuffles, no gate)
        float invq[4];
        #pragma unroll
        for (int q = 0; q < 4; ++q) invq[q] = frcp(osum[q]);
        #pragma unroll
        for (int et = 0; et < 2; ++et){
            const f32x4 oo = et ? o1 : o0;
            #pragma unroll
            for (int q = 0; q < 4; ++q){
                const int i = i0 + g*4 + q;
                const size_t pos = ROWPASS ? ((size_t)r*NN + i) : ((size_t)i*NN + r);
                const size_t off = pos*DD + h*DHH + et*16 + li;
                Aout[off] = f2b(oo[q] * invq[q]);
            }
        }
    }
}

// ---------------- host-side launch ----------------
extern "C" void kernel_launch(void* const* d_in, const int* in_sizes, int n_in,
                              void* d_out, int out_size, void* d_ws, size_t ws_size,
                              hipStream_t stream)
{
    const float* x = (const float*)d_in[0];
    float* out = (float*)d_out;
    char* ws = (char*)d_ws;

    u16*   xn   = (u16*)ws;                                   // NP*DD bf16 (aliased as attn out)
    float* bias = (float*)(ws + (size_t)NP*DD*2);             // NH*NP f32, [h][i][j], *LOG2E
    u16*   Pq   = (u16*)(ws + (size_t)NP*DD*2 + (size_t)NH*NP*4);
    u16*   Pk   = Pq + (size_t)NP*DD;
    u16*   Pv   = Pk + (size_t)NP*DD;
    u16*   Pg   = Pv + (size_t)NP*DD;
    u16*   Wpck = Pg + (size_t)NP*DD;                          // 10*2048*8 bf16
    u16*   Aatt = xn;   // xn is dead after the projection GEMM

    // one-time weight pack (both passes): per pass {wq, wkv_K, wkv_V, wg, wo}
    {
        const float* w0 = (const float*)d_in[4];               // o_wq
        const float* w1 = (const float*)d_in[5];               // o_wkv (K rows)
        const float* w2 = (const float*)d_in[5] + DD*DD;       // o_wkv (V rows)
        const float* w3 = (const float*)d_in[6];               // o_wg
        const float* w4 = (const float*)d_in[8];               // o_wo
        const float* w5 = (const float*)d_in[13];              // i_wq
        const float* w6 = (const float*)d_in[14];              // i_wkv (K rows)
        const float* w7 = (const float*)d_in[14] + DD*DD;      // i_wkv (V rows)
        const float* w8 = (const float*)d_in[15];              // i_wg
        const float* w9 = (const float*)d_in[17];              // i_wo
        k_pack<<<80, 256, 0, stream>>>(w0,w1,w2,w3,w4,w5,w6,w7,w8,w9, Wpck);
    }

    for (int pass = 0; pass < 2; ++pass){
        void* const* W = d_in + 1 + pass*9;
        const float* ng = (const float*)W[0];
        const float* nb = (const float*)W[1];
        const float* wb = (const float*)W[2];
        const float* bg = (const float*)W[6];
        const float* bo = (const float*)W[8];
        const float* xin = (pass == 0) ? x : out;
        const u16* Wp = Wpck + (size_t)pass*5*2048*8;

        k_ln_bias<<<NP/4, 256, 0, stream>>>(xin, ng, nb, wb, xn, bias);
        k_qkvg<<<NP/128, 256, 0, stream>>>(xn, Wp, bg, Pq, Pk, Pv, Pg);
        if (pass == 0) k_attn_mfma<1><<<dim3(NH, NN), 256, 0, stream>>>(Pq, Pk, Pv, bias, Aatt);
        else           k_attn_mfma<0><<<dim3(NH, NN), 256, 0, stream>>>(Pq, Pk, Pv, bias, Aatt);
        k_oproj<<<NP/128, 256, 0, stream>>>(Aatt, Pg, Wp, out, bo, xin);
    }
}

// Round 8
// 383.818 us; speedup vs baseline: 1.2403x; 1.2403x over previous
//
#include <hip/hip_runtime.h>
#include <hip/hip_bf16.h>

typedef unsigned short u16;
typedef unsigned int   u32;
typedef __attribute__((ext_vector_type(8))) short short8;
typedef __attribute__((ext_vector_type(4))) float f32x4;

#define NN 320
#define NP (NN*NN)
#define DD 128
#define NH 4
#define DHH 32
#define QSCALE 0.17677669529663687f
#define LOG2E  1.4426950408889634f

#define MFMA16(A,B,C) __builtin_amdgcn_mfma_f32_16x16x32_bf16(A,B,C,0,0,0)

__device__ __forceinline__ float b2f(u16 u){
    union { u32 i; float f; } v; v.i = ((u32)u) << 16; return v.f;
}
__device__ __forceinline__ u16 f2b(float f){
    union { float f; u32 i; } v; v.f = f;
    u32 x = v.i;
    u32 r = x + 0x7fffu + ((x >> 16) & 1u);
    return (u16)(r >> 16);
}
__device__ __forceinline__ u32 cvtpk(float lo, float hi){
    u32 r; asm("v_cvt_pk_bf16_f32 %0, %1, %2" : "=v"(r) : "v"(lo), "v"(hi)); return r;
}
__device__ __forceinline__ float fexp2(float x){
    float r; asm("v_exp_f32 %0, %1" : "=v"(r) : "v"(x)); return r;
}
__device__ __forceinline__ float frcp(float x){
    float r; asm("v_rcp_f32 %0, %1" : "=v"(r) : "v"(x)); return r;
}

// ---------------- Weight pre-pack: f32 [e][k] -> bf16 fragment-ordered ----------------
__global__ __launch_bounds__(256) void k_pack(
    const float* w0, const float* w1, const float* w2, const float* w3, const float* w4,
    const float* w5, const float* w6, const float* w7, const float* w8, const float* w9,
    u16* __restrict__ Wp)
{
    const int m = blockIdx.x >> 3;
    const int rem = ((blockIdx.x & 7) << 8) + threadIdx.x;
    const float* src;
    switch(m){
        case 0: src=w0; break; case 1: src=w1; break; case 2: src=w2; break;
        case 3: src=w3; break; case 4: src=w4; break; case 5: src=w5; break;
        case 6: src=w6; break; case 7: src=w7; break; case 8: src=w8; break;
        default: src=w9; break;
    }
    const float4 a = *(const float4*)(src + (size_t)rem*8);
    const float4 b = *(const float4*)(src + (size_t)rem*8 + 4);
    union { uint4 q; u16 us[8]; } ww;
    ww.us[0]=f2b(a.x); ww.us[1]=f2b(a.y); ww.us[2]=f2b(a.z); ww.us[3]=f2b(a.w);
    ww.us[4]=f2b(b.x); ww.us[5]=f2b(b.y); ww.us[6]=f2b(b.z); ww.us[7]=f2b(b.w);
    *(uint4*)(Wp + ((size_t)m*2048 + rem)*8) = ww.q;
}

// ---------------- LayerNorm + edge-bias (bias stored in attn-tiled layout) ----------------
// biasT[(((h*20+it)*2+ch)*10+jt)*4+g][li][q] = bias[h][i=it*16+li][j=ch*160+jt*16+g*4+q] * LOG2E
__global__ __launch_bounds__(256) void k_ln_bias(
    const float* __restrict__ xin, const float* __restrict__ ng, const float* __restrict__ nb,
    const float* __restrict__ wb, u16* __restrict__ xn, float* __restrict__ biasT)
{
    const int w = threadIdx.x >> 6, lane = threadIdx.x & 63;
    const int p = blockIdx.x * 4 + w;
    const int d0 = lane * 2;
    const float2 xp = *(const float2*)(xin + (size_t)p*DD + d0);
    const float x0 = xp.x, x1 = xp.y;
    float s = x0 + x1;
    #pragma unroll
    for (int m = 1; m < 64; m <<= 1) s += __shfl_xor(s, m);
    const float mu = s * (1.f/128.f);
    const float dx0 = x0 - mu, dx1 = x1 - mu;
    float vv = dx0*dx0 + dx1*dx1;
    #pragma unroll
    for (int m = 1; m < 64; m <<= 1) vv += __shfl_xor(vv, m);
    const float rstd = rsqrtf(vv * (1.f/128.f) + 1e-5f);
    const float2 gp = *(const float2*)(ng + d0);
    const float2 bp = *(const float2*)(nb + d0);
    const float y0 = dx0*rstd*gp.x + bp.x;
    const float y1 = dx1*rstd*gp.y + bp.y;
    const u32 ow = (u32)f2b(y0) | ((u32)f2b(y1) << 16);
    *(u32*)(xn + (size_t)p*DD + d0) = ow;

    const int pi = p / NN, pj = p - pi*NN;
    const int it = pi >> 4, lb = pi & 15;
    const int ch = (pj >= 160) ? 1 : 0;
    const int jj = pj - ch*160;
    const int jt = jj >> 4, rr = jj & 15;
    const int gb = rr >> 2, qb = rr & 3;
    #pragma unroll
    for (int h = 0; h < NH; ++h){
        const float2 wp = *(const float2*)(wb + h*DD + d0);
        float bb = x0*wp.x + x1*wp.y;
        #pragma unroll
        for (int m = 1; m < 64; m <<= 1) bb += __shfl_xor(bb, m);
        if (lane == 0){
            const size_t idx = (((((size_t)h*20 + it)*2 + ch)*10 + jt)*4 + gb)*64 + lb*4 + qb;
            biasT[idx] = bb * LOG2E;
        }
    }
}

// ---------------- Fused QKVG GEMM (swapped operands; head-major P outputs) ----------------
// p=0: Q (*QSCALE*LOG2E)  p=1: K  p=2: V   -> [h][pos][32] head-major
// p=3: G (sigmoid(+bg))                     -> [pos][128]
__global__ __launch_bounds__(256) void k_qkvg(
    const u16* __restrict__ Amat, const u16* __restrict__ Wp, const float* __restrict__ bg,
    u16* __restrict__ Pq, u16* __restrict__ Pk, u16* __restrict__ Pv, u16* __restrict__ Pg)
{
    __shared__ u16 As[128*128];   // [row][k], 16B-slot swizzle: slot ^= row&7
    const int tid = threadIdx.x;
    const int pbase = blockIdx.x * 128;

    #pragma unroll
    for (int c = 0; c < 8; ++c){
        const int flat = tid + c*256;
        const int row = flat >> 4, s = flat & 15;
        const uint4 a4 = *(const uint4*)(Amat + (size_t)(pbase+row)*DD + s*8);
        *(uint4*)&As[row*128 + ((s ^ (row & 7)) << 3)] = a4;
    }
    __syncthreads();

    const int w = tid >> 6, l = tid & 63;
    const int li = l & 15, g = l >> 4;
    const int wr = w >> 1, wc = w & 1;

    #pragma unroll
    for (int p = 0; p < 4; ++p){
        f32x4 acc[4][4] = {};
        #pragma unroll
        for (int ks = 0; ks < 4; ++ks){
            const int slot = ks*4 + g;
            short8 af[4];
            #pragma unroll
            for (int mt = 0; mt < 4; ++mt){
                const int row = wr*64 + mt*16 + li;
                af[mt] = *(const short8*)&As[row*128 + ((slot ^ (row & 7)) << 3)];
            }
            #pragma unroll
            for (int nt = 0; nt < 4; ++nt){
                const int e = wc*64 + nt*16 + li;
                const short8 wf = *(const short8*)(Wp + ((size_t)p*2048 + e*16 + slot)*8);
                #pragma unroll
                for (int mt = 0; mt < 4; ++mt)
                    acc[mt][nt] = MFMA16(wf, af[mt], acc[mt][nt]);   // D[e][pos]
            }
        }

        u16* Op = (p == 0) ? Pq : (p == 1) ? Pk : Pv;
        #pragma unroll
        for (int mt = 0; mt < 4; ++mt){
            const int pos = pbase + wr*64 + mt*16 + li;
            #pragma unroll
            for (int nt = 0; nt < 4; ++nt){
                const int eb = wc*64 + nt*16 + g*4;     // + q, 4 consecutive e per lane
                float v[4];
                #pragma unroll
                for (int q = 0; q < 4; ++q) v[q] = acc[mt][nt][q];
                if (p == 0){
                    #pragma unroll
                    for (int q = 0; q < 4; ++q) v[q] *= (QSCALE * LOG2E);
                } else if (p == 3){
                    #pragma unroll
                    for (int q = 0; q < 4; ++q) v[q] = frcp(1.f + fexp2(-LOG2E*(v[q] + bg[eb+q])));
                }
                uint2 o;
                o.x = cvtpk(v[0], v[1]);
                o.y = cvtpk(v[2], v[3]);
                if (p < 3){
                    u16* dst = Op + ((size_t)(eb >> 5)*NP + pos)*32 + (eb & 31);
                    *(uint2*)dst = o;
                } else {
                    *(uint2*)(Pg + (size_t)pos*DD + eb) = o;
                }
            }
        }
    }
}

// ---------------- Output projection (swapped; float4 epilogue) ----------------
__global__ __launch_bounds__(256) void k_oproj(
    const u16* __restrict__ Aatt, const u16* __restrict__ Pg, const u16* __restrict__ Wp,
    float* __restrict__ Outp, const float* __restrict__ bov, const float* __restrict__ xres)
{
    __shared__ u16 As[128*128];
    const int tid = threadIdx.x;
    const int pbase = blockIdx.x * 128;

    #pragma unroll
    for (int c = 0; c < 8; ++c){
        const int flat = tid + c*256;
        const int row = flat >> 4, s = flat & 15;
        const size_t off = (size_t)(pbase+row)*DD + s*8;
        union { uint4 q; u16 us[8]; } ua, ug;
        ua.q = *(const uint4*)(Aatt + off);
        ug.q = *(const uint4*)(Pg + off);
        uint4 o;
        o.x = cvtpk(b2f(ua.us[0])*b2f(ug.us[0]), b2f(ua.us[1])*b2f(ug.us[1]));
        o.y = cvtpk(b2f(ua.us[2])*b2f(ug.us[2]), b2f(ua.us[3])*b2f(ug.us[3]));
        o.z = cvtpk(b2f(ua.us[4])*b2f(ug.us[4]), b2f(ua.us[5])*b2f(ug.us[5]));
        o.w = cvtpk(b2f(ua.us[6])*b2f(ug.us[6]), b2f(ua.us[7])*b2f(ug.us[7]));
        *(uint4*)&As[row*128 + ((s ^ (row & 7)) << 3)] = o;
    }
    __syncthreads();

    const int w = tid >> 6, l = tid & 63;
    const int li = l & 15, g = l >> 4;
    const int wr = w >> 1, wc = w & 1;
    f32x4 acc[4][4] = {};

    #pragma unroll
    for (int ks = 0; ks < 4; ++ks){
        const int slot = ks*4 + g;
        short8 af[4];
        #pragma unroll
        for (int mt = 0; mt < 4; ++mt){
            const int row = wr*64 + mt*16 + li;
            af[mt] = *(const short8*)&As[row*128 + ((slot ^ (row & 7)) << 3)];
        }
        #pragma unroll
        for (int nt = 0; nt < 4; ++nt){
            const int e = wc*64 + nt*16 + li;
            const short8 wf = *(const short8*)(Wp + ((size_t)4*2048 + e*16 + slot)*8);
            #pragma unroll
            for (int mt = 0; mt < 4; ++mt)
                acc[mt][nt] = MFMA16(wf, af[mt], acc[mt][nt]);   // D[d][pos]
        }
    }

    #pragma unroll
    for (int mt = 0; mt < 4; ++mt){
        const int pos = pbase + wr*64 + mt*16 + li;
        #pragma unroll
        for (int nt = 0; nt < 4; ++nt){
            const int d0 = wc*64 + nt*16 + g*4;
            const float4 xr = *(const float4*)(xres + (size_t)pos*DD + d0);
            const float4 bo4 = *(const float4*)(bov + d0);
            float4 o;
            o.x = acc[mt][nt][0] + bo4.x + xr.x;
            o.y = acc[mt][nt][1] + bo4.y + xr.y;
            o.z = acc[mt][nt][2] + bo4.z + xr.z;
            o.w = acc[mt][nt][3] + bo4.w + xr.w;
            *(float4*)(Outp + (size_t)pos*DD + d0) = o;
        }
    }
}

// ---------------- MFMA attention: one block per (h, r), 4 waves x 5 Q-tiles ----------------
// Head-major P inputs; tiled bias (1KB/wave coalesced C-loads); 2-chunk online softmax;
// swapped PV (O[e][i=li]) + lane-local VALU row-sum (no ones-MFMA, no epilogue shuffles).
template<int ROWPASS>
__global__ __launch_bounds__(256) void k_attn_mfma(
    const u16* __restrict__ Pq, const u16* __restrict__ Pk, const u16* __restrict__ Pv,
    const float* __restrict__ biasT, u16* __restrict__ Aout)
{
    __shared__ u16 ksm[320*32];  // [j][e], 16B-slot swizzle: slot ^= (j>>1)&3
    __shared__ u16 vt[32*320];   // [e][j'], j' = PV-permuted j, slot swizzle: slot ^= e&7
    const int h = blockIdx.x, r = blockIdx.y;
    const int tid = threadIdx.x;

    const u16* Kh = Pk + (size_t)h*NP*32;
    const u16* Vh = Pv + (size_t)h*NP*32;
    const u16* Qh = Pq + (size_t)h*NP*32;

    #pragma unroll
    for (int c = 0; c < 5; ++c){
        const int flat = tid + c*256;      // 0..1279
        const int j = flat >> 2, s = flat & 3;
        const size_t pos = ROWPASS ? ((size_t)r*NN + j) : ((size_t)j*NN + r);
        const uint4 k4 = *(const uint4*)(Kh + pos*32 + s*8);
        *(uint4*)&ksm[j*32 + ((s ^ ((j >> 1) & 3)) << 3)] = k4;
        const uint4 v4 = *(const uint4*)(Vh + pos*32 + s*8);
        union { uint4 q; u16 us[8]; } vu; vu.q = v4;
        const int jp = (j & ~31) + ((j >> 2) & 3)*8 + ((j >> 4) & 1)*4 + (j & 3);
        #pragma unroll
        for (int u = 0; u < 8; ++u){
            const int e = s*8 + u;
            vt[e*320 + (((jp >> 3) ^ (e & 7)) << 3) + (jp & 7)] = vu.us[u];
        }
    }
    __syncthreads();

    const int w = tid >> 6, l = tid & 63;
    const int li = l & 15, g = l >> 4;

    for (int t = 0; t < 5; ++t){
        const int it = w + t*4;
        const int i0 = it * 16;
        const int iq = i0 + li;
        const size_t qpos = ROWPASS ? ((size_t)r*NN + iq) : ((size_t)iq*NN + r);
        const short8 qf = *(const short8*)(Qh + qpos*32 + g*8);

        float mrun = -3.0e38f;
        float rsum = 0.f;
        f32x4 o0 = {0.f,0.f,0.f,0.f}, o1 = {0.f,0.f,0.f,0.f};

        #pragma unroll
        for (int ch = 0; ch < 2; ++ch){
            // bias C-operands: contiguous 1KB per wave per jt
            f32x4 st[10];
            const float* bp = biasT + ((((size_t)h*20 + it)*2 + ch)*10)*256 + g*64 + li*4;
            #pragma unroll
            for (int jt = 0; jt < 10; ++jt)
                st[jt] = *(const f32x4*)(bp + jt*256);

            #pragma unroll
            for (int jt = 0; jt < 10; ++jt){
                const int jr = ch*160 + jt*16 + li;
                const short8 kf = *(const short8*)&ksm[jr*32 + ((g ^ ((jr >> 1) & 3)) << 3)];
                st[jt] = MFMA16(kf, qf, st[jt]);     // S[j][i=li]
            }

            // chunk max (row-wide over the 4 g-lanes)
            float mx = -3.0e38f;
            #pragma unroll
            for (int jt = 0; jt < 10; ++jt)
                mx = fmaxf(mx, fmaxf(fmaxf(st[jt][0], st[jt][1]), fmaxf(st[jt][2], st[jt][3])));
            mx = fmaxf(mx, __shfl_xor(mx, 16));
            mx = fmaxf(mx, __shfl_xor(mx, 32));
            const float mnew = fmaxf(mrun, mx);
            const float sc = fexp2(mrun - mnew);
            #pragma unroll
            for (int q = 0; q < 4; ++q){ o0[q] *= sc; o1[q] *= sc; }
            rsum *= sc;
            mrun = mnew;

            // exp2 + lane-local partial row-sum
            #pragma unroll
            for (int jt = 0; jt < 10; ++jt){
                #pragma unroll
                for (int q = 0; q < 4; ++q){
                    const float e = fexp2(st[jt][q] - mrun);
                    st[jt][q] = e; rsum += e;
                }
            }

            // PV swapped: O[e][i=li]; V as A-operand, P as B-operand
            #pragma unroll
            for (int kt = 0; kt < 5; ++kt){
                union { u32 u[4]; short8 s8; } pu;
                pu.u[0] = cvtpk(st[2*kt][0],   st[2*kt][1]);
                pu.u[1] = cvtpk(st[2*kt][2],   st[2*kt][3]);
                pu.u[2] = cvtpk(st[2*kt+1][0], st[2*kt+1][1]);
                pu.u[3] = cvtpk(st[2*kt+1][2], st[2*kt+1][3]);
                const int ktg = ch*5 + kt;
                const int slot = ((ktg*4 + g) ^ (li & 7)) << 3;
                const short8 v0 = *(const short8*)&vt[li*320 + slot];
                const short8 v1 = *(const short8*)&vt[(16+li)*320 + slot];
                o0 = MFMA16(v0, pu.s8, o0);   // e 0..15
                o1 = MFMA16(v1, pu.s8, o1);   // e 16..31
            }
        }

        // row-sum across g-lanes; inv is lane-local for row i=li
        rsum += __shfl_xor(rsum, 16);
        rsum += __shfl_xor(rsum, 32);
        const float inv = frcp(rsum);

        // epilogue: lane (li,g) holds O[e = et*16 + g*4 + q][i = li] -> 8B stores
        u16* dst = Aout + qpos*DD + h*DHH;
        #pragma unroll
        for (int et = 0; et < 2; ++et){
            const f32x4 oo = et ? o1 : o0;
            uint2 o;
            o.x = cvtpk(oo[0]*inv, oo[1]*inv);
            o.y = cvtpk(oo[2]*inv, oo[3]*inv);
            *(uint2*)(dst + et*16 + g*4) = o;
        }
    }
}

// ---------------- host-side launch ----------------
extern "C" void kernel_launch(void* const* d_in, const int* in_sizes, int n_in,
                              void* d_out, int out_size, void* d_ws, size_t ws_size,
                              hipStream_t stream)
{
    const float* x = (const float*)d_in[0];
    float* out = (float*)d_out;
    char* ws = (char*)d_ws;

    u16*   xn    = (u16*)ws;                                  // NP*DD bf16 (aliased as attn out)
    float* biasT = (float*)(ws + (size_t)NP*DD*2);            // NH*NP f32, attn-tiled
    u16*   Pq    = (u16*)(ws + (size_t)NP*DD*2 + (size_t)NH*NP*4);  // head-major [h][pos][32]
    u16*   Pk    = Pq + (size_t)NP*DD;
    u16*   Pv    = Pk + (size_t)NP*DD;
    u16*   Pg    = Pv + (size_t)NP*DD;                        // [pos][128]
    u16*   Wpck  = Pg + (size_t)NP*DD;                        // 10*2048*8 bf16
    u16*   Aatt  = xn;   // xn is dead after the projection GEMM

    {
        const float* w0 = (const float*)d_in[4];               // o_wq
        const float* w1 = (const float*)d_in[5];               // o_wkv (K rows)
        const float* w2 = (const float*)d_in[5] + DD*DD;       // o_wkv (V rows)
        const float* w3 = (const float*)d_in[6];               // o_wg
        const float* w4 = (const float*)d_in[8];               // o_wo
        const float* w5 = (const float*)d_in[13];              // i_wq
        const float* w6 = (const float*)d_in[14];              // i_wkv (K rows)
        const float* w7 = (const float*)d_in[14] + DD*DD;      // i_wkv (V rows)
        const float* w8 = (const float*)d_in[15];              // i_wg
        const float* w9 = (const float*)d_in[17];              // i_wo
        k_pack<<<80, 256, 0, stream>>>(w0,w1,w2,w3,w4,w5,w6,w7,w8,w9, Wpck);
    }

    for (int pass = 0; pass < 2; ++pass){
        void* const* W = d_in + 1 + pass*9;
        const float* ng = (const float*)W[0];
        const float* nb = (const float*)W[1];
        const float* wb = (const float*)W[2];
        const float* bg = (const float*)W[6];
        const float* bo = (const float*)W[8];
        const float* xin = (pass == 0) ? x : out;
        const u16* Wp = Wpck + (size_t)pass*5*2048*8;

        k_ln_bias<<<NP/4, 256, 0, stream>>>(xin, ng, nb, wb, xn, biasT);
        k_qkvg<<<NP/128, 256, 0, stream>>>(xn, Wp, bg, Pq, Pk, Pv, Pg);
        if (pass == 0) k_attn_mfma<1><<<dim3(NH, NN), 256, 0, stream>>>(Pq, Pk, Pv, biasT, Aatt);
        else           k_attn_mfma<0><<<dim3(NH, NN), 256, 0, stream>>>(Pq, Pk, Pv, biasT, Aatt);
        k_oproj<<<NP/128, 256, 0, stream>>>(Aatt, Pg, Wp, out, bo, xin);
    }
}

// Round 9
// 278.921 us; speedup vs baseline: 1.7067x; 1.3761x over previous
//
#include <hip/hip_runtime.h>
#include <hip/hip_bf16.h>

typedef unsigned short u16;
typedef unsigned int   u32;
typedef __attribute__((ext_vector_type(8))) short short8;
typedef __attribute__((ext_vector_type(4))) float f32x4;

#define NN 320
#define NP (NN*NN)
#define DD 128
#define NH 4
#define DHH 32
#define QSCALE 0.17677669529663687f
#define LOG2E  1.4426950408889634f

#define MFMA16(A,B,C) __builtin_amdgcn_mfma_f32_16x16x32_bf16(A,B,C,0,0,0)

__device__ __forceinline__ float b2f(u16 u){
    union { u32 i; float f; } v; v.i = ((u32)u) << 16; return v.f;
}
__device__ __forceinline__ u16 f2b(float f){
    union { float f; u32 i; } v; v.f = f;
    u32 x = v.i;
    u32 r = x + 0x7fffu + ((x >> 16) & 1u);
    return (u16)(r >> 16);
}
__device__ __forceinline__ u32 cvtpk(float lo, float hi){
    u32 r; asm("v_cvt_pk_bf16_f32 %0, %1, %2" : "=v"(r) : "v"(lo), "v"(hi)); return r;
}
__device__ __forceinline__ float fexp2(float x){
    float r; asm("v_exp_f32 %0, %1" : "=v"(r) : "v"(x)); return r;
}
__device__ __forceinline__ float frcp(float x){
    float r; asm("v_rcp_f32 %0, %1" : "=v"(r) : "v"(x)); return r;
}

// ---------------- Weight pre-pack: f32 [e][k] -> bf16, SLOT-SWIZZLED fragment order ----
// dest index = e*16 + (slot ^ (e&15));  GEMMs stage this linearly into LDS and read with
// the same XOR -> bank-spread ds_read_b128.
__global__ __launch_bounds__(256) void k_pack(
    const float* w0, const float* w1, const float* w2, const float* w3, const float* w4,
    const float* w5, const float* w6, const float* w7, const float* w8, const float* w9,
    u16* __restrict__ Wp)
{
    const int m = blockIdx.x >> 3;
    const int rem = ((blockIdx.x & 7) << 8) + threadIdx.x;   // 0..2047
    const float* src;
    switch(m){
        case 0: src=w0; break; case 1: src=w1; break; case 2: src=w2; break;
        case 3: src=w3; break; case 4: src=w4; break; case 5: src=w5; break;
        case 6: src=w6; break; case 7: src=w7; break; case 8: src=w8; break;
        default: src=w9; break;
    }
    const float4 a = *(const float4*)(src + (size_t)rem*8);
    const float4 b = *(const float4*)(src + (size_t)rem*8 + 4);
    union { uint4 q; u16 us[8]; } ww;
    ww.us[0]=f2b(a.x); ww.us[1]=f2b(a.y); ww.us[2]=f2b(a.z); ww.us[3]=f2b(a.w);
    ww.us[4]=f2b(b.x); ww.us[5]=f2b(b.y); ww.us[6]=f2b(b.z); ww.us[7]=f2b(b.w);
    const int e = rem >> 4, slot = rem & 15;
    const int dst = (e << 4) + (slot ^ (e & 15));
    *(uint4*)(Wp + ((size_t)m*2048 + dst)*8) = ww.q;
}

// ---------------- Fused LN + edge-bias + QKVG GEMM ----------------
// Staging threads (16 per row) LayerNorm the row in-register (shfl_xor reduces),
// write bf16 As, compute the 4 bias dots on raw x, thread s<4 writes biasT (tiled).
// Per phase: W tile staged to LDS (pre-swizzled source), fragments via ds_read_b128.
// p=0: Q (*QSCALE*LOG2E)  p=1: K  p=2: V  -> [h][pos][32] head-major ; p=3: G -> [pos][128]
__global__ __launch_bounds__(256) void k_lnqkvg(
    const float* __restrict__ xin, const float* __restrict__ ng, const float* __restrict__ nb,
    const float* __restrict__ wb, const u16* __restrict__ Wp, const float* __restrict__ bg,
    float* __restrict__ biasT,
    u16* __restrict__ Pq, u16* __restrict__ Pk, u16* __restrict__ Pv, u16* __restrict__ Pg)
{
    __shared__ u16 As[128*128];   // 32 KB, 16B-slot swizzle: slot ^= row&7
    __shared__ u16 Ws[128*128];   // 32 KB, one phase's W tile (pre-swizzled layout)
    const int tid = threadIdx.x;
    const int pbase = blockIdx.x * 128;
    const int s  = tid & 15;      // constant across c (256 % 16 == 0)
    const int d0 = s * 8;

    const float4 g0 = *(const float4*)(ng + d0), g1 = *(const float4*)(ng + d0 + 4);
    const float4 b0 = *(const float4*)(nb + d0), b1 = *(const float4*)(nb + d0 + 4);

    #pragma unroll
    for (int c = 0; c < 8; ++c){
        const int row = (tid >> 4) + c*16;
        const int p = pbase + row;
        const float* xr = xin + (size_t)p*DD + d0;
        const float4 xa = *(const float4*)xr, xb = *(const float4*)(xr + 4);
        const float xs[8] = {xa.x,xa.y,xa.z,xa.w,xb.x,xb.y,xb.z,xb.w};
        float sum = 0.f, sq = 0.f;
        #pragma unroll
        for (int u = 0; u < 8; ++u){ sum += xs[u]; sq += xs[u]*xs[u]; }
        #pragma unroll
        for (int m = 1; m < 16; m <<= 1){
            sum += __shfl_xor(sum, m);
            sq  += __shfl_xor(sq,  m);
        }
        const float mu = sum * (1.f/128.f);
        const float var = fmaxf(sq * (1.f/128.f) - mu*mu, 0.f);
        const float rstd = rsqrtf(var + 1e-5f);
        const float gg[8] = {g0.x,g0.y,g0.z,g0.w,g1.x,g1.y,g1.z,g1.w};
        const float bbv[8]= {b0.x,b0.y,b0.z,b0.w,b1.x,b1.y,b1.z,b1.w};
        float y[8];
        #pragma unroll
        for (int u = 0; u < 8; ++u) y[u] = (xs[u]-mu)*rstd*gg[u] + bbv[u];
        uint4 o;
        o.x = cvtpk(y[0],y[1]); o.y = cvtpk(y[2],y[3]);
        o.z = cvtpk(y[4],y[5]); o.w = cvtpk(y[6],y[7]);
        *(uint4*)&As[row*128 + ((s ^ (row & 7)) << 3)] = o;

        // edge-bias dots on RAW x, one reduce chain per head
        float bh0=0.f, bh1=0.f, bh2=0.f, bh3=0.f;
        {
            const float4 wa = *(const float4*)(wb + 0*DD + d0), wbv_ = *(const float4*)(wb + 0*DD + d0 + 4);
            const float wv[8] = {wa.x,wa.y,wa.z,wa.w,wbv_.x,wbv_.y,wbv_.z,wbv_.w};
            #pragma unroll
            for (int u = 0; u < 8; ++u) bh0 += xs[u]*wv[u];
        }
        {
            const float4 wa = *(const float4*)(wb + 1*DD + d0), wbv_ = *(const float4*)(wb + 1*DD + d0 + 4);
            const float wv[8] = {wa.x,wa.y,wa.z,wa.w,wbv_.x,wbv_.y,wbv_.z,wbv_.w};
            #pragma unroll
            for (int u = 0; u < 8; ++u) bh1 += xs[u]*wv[u];
        }
        {
            const float4 wa = *(const float4*)(wb + 2*DD + d0), wbv_ = *(const float4*)(wb + 2*DD + d0 + 4);
            const float wv[8] = {wa.x,wa.y,wa.z,wa.w,wbv_.x,wbv_.y,wbv_.z,wbv_.w};
            #pragma unroll
            for (int u = 0; u < 8; ++u) bh2 += xs[u]*wv[u];
        }
        {
            const float4 wa = *(const float4*)(wb + 3*DD + d0), wbv_ = *(const float4*)(wb + 3*DD + d0 + 4);
            const float wv[8] = {wa.x,wa.y,wa.z,wa.w,wbv_.x,wbv_.y,wbv_.z,wbv_.w};
            #pragma unroll
            for (int u = 0; u < 8; ++u) bh3 += xs[u]*wv[u];
        }
        #pragma unroll
        for (int m = 1; m < 16; m <<= 1){
            bh0 += __shfl_xor(bh0, m); bh1 += __shfl_xor(bh1, m);
            bh2 += __shfl_xor(bh2, m); bh3 += __shfl_xor(bh3, m);
        }
        if (s < 4){
            const float bsel = (s == 0) ? bh0 : (s == 1) ? bh1 : (s == 2) ? bh2 : bh3;
            const int pi = p / NN, pj = p - pi*NN;
            const int it = pi >> 4, lb = pi & 15;
            const int ch = (pj >= 160) ? 1 : 0;
            const int jj = pj - ch*160;
            const int jt = jj >> 4, rr = jj & 15;
            const int gb = rr >> 2, qb = rr & 3;
            const size_t idx = (((((size_t)s*20 + it)*2 + ch)*10 + jt)*4 + gb)*64 + lb*4 + qb;
            biasT[idx] = bsel * LOG2E;
        }
    }

    const int w = tid >> 6, l = tid & 63;
    const int li = l & 15, g = l >> 4;
    const int wr = w >> 1, wc = w & 1;

    #pragma unroll
    for (int p = 0; p < 4; ++p){
        if (p > 0) __syncthreads();          // drain Ws(p-1) reads
        #pragma unroll
        for (int c = 0; c < 8; ++c){
            const int flat = tid + c*256;
            const uint4 wv = *(const uint4*)(Wp + ((size_t)p*2048 + flat)*8);
            *(uint4*)&Ws[flat*8] = wv;
        }
        __syncthreads();                     // Ws(p) ready (and As on p==0)

        f32x4 acc[4][4] = {};
        #pragma unroll
        for (int ks = 0; ks < 4; ++ks){
            const int slot = ks*4 + g;
            short8 af[4];
            #pragma unroll
            for (int mt = 0; mt < 4; ++mt){
                const int row = wr*64 + mt*16 + li;
                af[mt] = *(const short8*)&As[row*128 + ((slot ^ (row & 7)) << 3)];
            }
            #pragma unroll
            for (int nt = 0; nt < 4; ++nt){
                const int e = wc*64 + nt*16 + li;
                const short8 wf = *(const short8*)&Ws[((e << 4) + (slot ^ (e & 15))) * 8];
                #pragma unroll
                for (int mt = 0; mt < 4; ++mt)
                    acc[mt][nt] = MFMA16(wf, af[mt], acc[mt][nt]);   // D[e][pos]
            }
        }

        u16* Op = (p == 0) ? Pq : (p == 1) ? Pk : Pv;
        #pragma unroll
        for (int mt = 0; mt < 4; ++mt){
            const int pos = pbase + wr*64 + mt*16 + li;
            #pragma unroll
            for (int nt = 0; nt < 4; ++nt){
                const int eb = wc*64 + nt*16 + g*4;
                float v[4];
                #pragma unroll
                for (int q = 0; q < 4; ++q) v[q] = acc[mt][nt][q];
                if (p == 0){
                    #pragma unroll
                    for (int q = 0; q < 4; ++q) v[q] *= (QSCALE * LOG2E);
                } else if (p == 3){
                    #pragma unroll
                    for (int q = 0; q < 4; ++q) v[q] = frcp(1.f + fexp2(-LOG2E*(v[q] + bg[eb+q])));
                }
                uint2 o;
                o.x = cvtpk(v[0], v[1]);
                o.y = cvtpk(v[2], v[3]);
                if (p < 3){
                    u16* dst = Op + ((size_t)(eb >> 5)*NP + pos)*32 + (eb & 31);
                    *(uint2*)dst = o;
                } else {
                    *(uint2*)(Pg + (size_t)pos*DD + eb) = o;
                }
            }
        }
    }
}

// ---------------- Output projection (gated staging; Ws in LDS; float4 epilogue) --------
__global__ __launch_bounds__(256) void k_oproj(
    const u16* __restrict__ Aatt, const u16* __restrict__ Pg, const u16* __restrict__ Wp,
    float* __restrict__ Outp, const float* __restrict__ bov, const float* __restrict__ xres)
{
    __shared__ u16 As[128*128];
    __shared__ u16 Ws[128*128];
    const int tid = threadIdx.x;
    const int pbase = blockIdx.x * 128;

    #pragma unroll
    for (int c = 0; c < 8; ++c){
        const int flat = tid + c*256;
        const int row = flat >> 4, s = flat & 15;
        const size_t off = (size_t)(pbase+row)*DD + s*8;
        union { uint4 q; u16 us[8]; } ua, ug;
        ua.q = *(const uint4*)(Aatt + off);
        ug.q = *(const uint4*)(Pg + off);
        uint4 o;
        o.x = cvtpk(b2f(ua.us[0])*b2f(ug.us[0]), b2f(ua.us[1])*b2f(ug.us[1]));
        o.y = cvtpk(b2f(ua.us[2])*b2f(ug.us[2]), b2f(ua.us[3])*b2f(ug.us[3]));
        o.z = cvtpk(b2f(ua.us[4])*b2f(ug.us[4]), b2f(ua.us[5])*b2f(ug.us[5]));
        o.w = cvtpk(b2f(ua.us[6])*b2f(ug.us[6]), b2f(ua.us[7])*b2f(ug.us[7]));
        *(uint4*)&As[row*128 + ((s ^ (row & 7)) << 3)] = o;
        const uint4 wv = *(const uint4*)(Wp + ((size_t)4*2048 + flat)*8);
        *(uint4*)&Ws[flat*8] = wv;
    }
    __syncthreads();

    const int w = tid >> 6, l = tid & 63;
    const int li = l & 15, g = l >> 4;
    const int wr = w >> 1, wc = w & 1;
    f32x4 acc[4][4] = {};

    #pragma unroll
    for (int ks = 0; ks < 4; ++ks){
        const int slot = ks*4 + g;
        short8 af[4];
        #pragma unroll
        for (int mt = 0; mt < 4; ++mt){
            const int row = wr*64 + mt*16 + li;
            af[mt] = *(const short8*)&As[row*128 + ((slot ^ (row & 7)) << 3)];
        }
        #pragma unroll
        for (int nt = 0; nt < 4; ++nt){
            const int e = wc*64 + nt*16 + li;
            const short8 wf = *(const short8*)&Ws[((e << 4) + (slot ^ (e & 15))) * 8];
            #pragma unroll
            for (int mt = 0; mt < 4; ++mt)
                acc[mt][nt] = MFMA16(wf, af[mt], acc[mt][nt]);   // D[d][pos]
        }
    }

    #pragma unroll
    for (int mt = 0; mt < 4; ++mt){
        const int pos = pbase + wr*64 + mt*16 + li;
        #pragma unroll
        for (int nt = 0; nt < 4; ++nt){
            const int d0 = wc*64 + nt*16 + g*4;
            const float4 xr = *(const float4*)(xres + (size_t)pos*DD + d0);
            const float4 bo4 = *(const float4*)(bov + d0);
            float4 o;
            o.x = acc[mt][nt][0] + bo4.x + xr.x;
            o.y = acc[mt][nt][1] + bo4.y + xr.y;
            o.z = acc[mt][nt][2] + bo4.z + xr.z;
            o.w = acc[mt][nt][3] + bo4.w + xr.w;
            *(float4*)(Outp + (size_t)pos*DD + d0) = o;
        }
    }
}

// ---------------- MFMA attention (unchanged from r8) ----------------
template<int ROWPASS>
__global__ __launch_bounds__(256) void k_attn_mfma(
    const u16* __restrict__ Pq, const u16* __restrict__ Pk, const u16* __restrict__ Pv,
    const float* __restrict__ biasT, u16* __restrict__ Aout)
{
    __shared__ u16 ksm[320*32];  // [j][e], 16B-slot swizzle: slot ^= (j>>1)&3
    __shared__ u16 vt[32*320];   // [e][j'], j' = PV-permuted j, slot swizzle: slot ^= e&7
    const int h = blockIdx.x, r = blockIdx.y;
    const int tid = threadIdx.x;

    const u16* Kh = Pk + (size_t)h*NP*32;
    const u16* Vh = Pv + (size_t)h*NP*32;
    const u16* Qh = Pq + (size_t)h*NP*32;

    #pragma unroll
    for (int c = 0; c < 5; ++c){
        const int flat = tid + c*256;
        const int j = flat >> 2, s = flat & 3;
        const size_t pos = ROWPASS ? ((size_t)r*NN + j) : ((size_t)j*NN + r);
        const uint4 k4 = *(const uint4*)(Kh + pos*32 + s*8);
        *(uint4*)&ksm[j*32 + ((s ^ ((j >> 1) & 3)) << 3)] = k4;
        const uint4 v4 = *(const uint4*)(Vh + pos*32 + s*8);
        union { uint4 q; u16 us[8]; } vu; vu.q = v4;
        const int jp = (j & ~31) + ((j >> 2) & 3)*8 + ((j >> 4) & 1)*4 + (j & 3);
        #pragma unroll
        for (int u = 0; u < 8; ++u){
            const int e = s*8 + u;
            vt[e*320 + (((jp >> 3) ^ (e & 7)) << 3) + (jp & 7)] = vu.us[u];
        }
    }
    __syncthreads();

    const int w = tid >> 6, l = tid & 63;
    const int li = l & 15, g = l >> 4;

    for (int t = 0; t < 5; ++t){
        const int it = w + t*4;
        const int i0 = it * 16;
        const int iq = i0 + li;
        const size_t qpos = ROWPASS ? ((size_t)r*NN + iq) : ((size_t)iq*NN + r);
        const short8 qf = *(const short8*)(Qh + qpos*32 + g*8);

        float mrun = -3.0e38f;
        float rsum = 0.f;
        f32x4 o0 = {0.f,0.f,0.f,0.f}, o1 = {0.f,0.f,0.f,0.f};

        #pragma unroll
        for (int ch = 0; ch < 2; ++ch){
            f32x4 st[10];
            const float* bp = biasT + ((((size_t)h*20 + it)*2 + ch)*10)*256 + g*64 + li*4;
            #pragma unroll
            for (int jt = 0; jt < 10; ++jt)
                st[jt] = *(const f32x4*)(bp + jt*256);

            #pragma unroll
            for (int jt = 0; jt < 10; ++jt){
                const int jr = ch*160 + jt*16 + li;
                const short8 kf = *(const short8*)&ksm[jr*32 + ((g ^ ((jr >> 1) & 3)) << 3)];
                st[jt] = MFMA16(kf, qf, st[jt]);     // S[j][i=li]
            }

            float mx = -3.0e38f;
            #pragma unroll
            for (int jt = 0; jt < 10; ++jt)
                mx = fmaxf(mx, fmaxf(fmaxf(st[jt][0], st[jt][1]), fmaxf(st[jt][2], st[jt][3])));
            mx = fmaxf(mx, __shfl_xor(mx, 16));
            mx = fmaxf(mx, __shfl_xor(mx, 32));
            const float mnew = fmaxf(mrun, mx);
            const float sc = fexp2(mrun - mnew);
            #pragma unroll
            for (int q = 0; q < 4; ++q){ o0[q] *= sc; o1[q] *= sc; }
            rsum *= sc;
            mrun = mnew;

            #pragma unroll
            for (int jt = 0; jt < 10; ++jt){
                #pragma unroll
                for (int q = 0; q < 4; ++q){
                    const float e = fexp2(st[jt][q] - mrun);
                    st[jt][q] = e; rsum += e;
                }
            }

            #pragma unroll
            for (int kt = 0; kt < 5; ++kt){
                union { u32 u[4]; short8 s8; } pu;
                pu.u[0] = cvtpk(st[2*kt][0],   st[2*kt][1]);
                pu.u[1] = cvtpk(st[2*kt][2],   st[2*kt][3]);
                pu.u[2] = cvtpk(st[2*kt+1][0], st[2*kt+1][1]);
                pu.u[3] = cvtpk(st[2*kt+1][2], st[2*kt+1][3]);
                const int ktg = ch*5 + kt;
                const int slot = ((ktg*4 + g) ^ (li & 7)) << 3;
                const short8 v0 = *(const short8*)&vt[li*320 + slot];
                const short8 v1 = *(const short8*)&vt[(16+li)*320 + slot];
                o0 = MFMA16(v0, pu.s8, o0);
                o1 = MFMA16(v1, pu.s8, o1);
            }
        }

        rsum += __shfl_xor(rsum, 16);
        rsum += __shfl_xor(rsum, 32);
        const float inv = frcp(rsum);

        u16* dst = Aout + qpos*DD + h*DHH;
        #pragma unroll
        for (int et = 0; et < 2; ++et){
            const f32x4 oo = et ? o1 : o0;
            uint2 o;
            o.x = cvtpk(oo[0]*inv, oo[1]*inv);
            o.y = cvtpk(oo[2]*inv, oo[3]*inv);
            *(uint2*)(dst + et*16 + g*4) = o;
        }
    }
}

// ---------------- host-side launch ----------------
extern "C" void kernel_launch(void* const* d_in, const int* in_sizes, int n_in,
                              void* d_out, int out_size, void* d_ws, size_t ws_size,
                              hipStream_t stream)
{
    const float* x = (const float*)d_in[0];
    float* out = (float*)d_out;
    char* ws = (char*)d_ws;

    u16*   Aatt  = (u16*)ws;                                  // NP*DD bf16
    float* biasT = (float*)(ws + (size_t)NP*DD*2);            // NH*NP f32, attn-tiled
    u16*   Pq    = (u16*)(ws + (size_t)NP*DD*2 + (size_t)NH*NP*4);  // [h][pos][32]
    u16*   Pk    = Pq + (size_t)NP*DD;
    u16*   Pv    = Pk + (size_t)NP*DD;
    u16*   Pg    = Pv + (size_t)NP*DD;                        // [pos][128]
    u16*   Wpck  = Pg + (size_t)NP*DD;                        // 10*2048*8 bf16 (swizzled)

    {
        const float* w0 = (const float*)d_in[4];               // o_wq
        const float* w1 = (const float*)d_in[5];               // o_wkv (K rows)
        const float* w2 = (const float*)d_in[5] + DD*DD;       // o_wkv (V rows)
        const float* w3 = (const float*)d_in[6];               // o_wg
        const float* w4 = (const float*)d_in[8];               // o_wo
        const float* w5 = (const float*)d_in[13];              // i_wq
        const float* w6 = (const float*)d_in[14];              // i_wkv (K rows)
        const float* w7 = (const float*)d_in[14] + DD*DD;      // i_wkv (V rows)
        const float* w8 = (const float*)d_in[15];              // i_wg
        const float* w9 = (const float*)d_in[17];              // i_wo
        k_pack<<<80, 256, 0, stream>>>(w0,w1,w2,w3,w4,w5,w6,w7,w8,w9, Wpck);
    }

    for (int pass = 0; pass < 2; ++pass){
        void* const* W = d_in + 1 + pass*9;
        const float* ng = (const float*)W[0];
        const float* nb = (const float*)W[1];
        const float* wb = (const float*)W[2];
        const float* bg = (const float*)W[6];
        const float* bo = (const float*)W[8];
        const float* xin = (pass == 0) ? x : out;
        const u16* Wp = Wpck + (size_t)pass*5*2048*8;

        k_lnqkvg<<<NP/128, 256, 0, stream>>>(xin, ng, nb, wb, Wp, bg, biasT, Pq, Pk, Pv, Pg);
        if (pass == 0) k_attn_mfma<1><<<dim3(NH, NN), 256, 0, stream>>>(Pq, Pk, Pv, biasT, Aatt);
        else           k_attn_mfma<0><<<dim3(NH, NN), 256, 0, stream>>>(Pq, Pk, Pv, biasT, Aatt);
        k_oproj<<<NP/128, 256, 0, stream>>>(Aatt, Pg, Wp, out, bo, xin);
    }
}